// Round 12
// baseline (436.187 us; speedup 1.0000x reference)
//
#include <hip/hip_runtime.h>
#include <hip/hip_fp16.h>
#include <hip/hip_cooperative_groups.h>
#include <math.h>

namespace cg = cooperative_groups;

#define N_NODES 50000
#define N_EDGES 600000
#define N_GRAPHS 64
#define DFEAT 128
#define H3 384
#define OUTD 10
#define SCAN_BLOCKS 196   // 196*256 = 50176 >= 50000
#define POOL_CHUNKS 16    // blocks per graph in pooling
#define APAD 136          // fp16 LDS row pad: 272B stride -> conflict-free b128 reads

typedef _Float16 f16x8 __attribute__((ext_vector_type(8)));
typedef float f32x4 __attribute__((ext_vector_type(4)));
typedef float f32x2 __attribute__((ext_vector_type(2)));

// ---------------- fused graph preprocessing (cooperative, 196 blocks x 256) ----------------
// phases: zero deg -> histogram+rank -> block partials -> 1-block scan -> offs/dinv -> CSR fill
__global__ __launch_bounds__(256) void k_graphprep(const int* __restrict__ ei, int* __restrict__ deg,
                                                   int* __restrict__ rank, int* __restrict__ part,
                                                   int* __restrict__ offs, float* __restrict__ dinv,
                                                   int* __restrict__ srcs) {
    cg::grid_group grid = cg::this_grid();
    __shared__ int red[256];
    __shared__ int buf[256];
    int tid = threadIdx.x, bid = blockIdx.x;
    int gthreads = gridDim.x * 256;
    int gtid = bid * 256 + tid;
    // phase 0: zero deg
    for (int i = gtid; i < N_NODES; i += gthreads) deg[i] = 0;
    grid.sync();
    // phase 1: in-degree histogram + per-edge rank
    for (int e = gtid; e < N_EDGES; e += gthreads) {
        int dst = ei[N_EDGES + e];
        rank[e] = atomicAdd(&deg[dst], 1);
    }
    grid.sync();
    // phase 2: per-block partial sums (256 nodes per block)
    int i = bid * 256 + tid;
    red[tid] = (i < N_NODES) ? deg[i] : 0;
    __syncthreads();
    for (int s = 128; s > 0; s >>= 1) {
        if (tid < s) red[tid] += red[tid + s];
        __syncthreads();
    }
    if (tid == 0) part[bid] = red[0];
    grid.sync();
    // phase 3: block 0 scans the partials -> exclusive bases (in place)
    if (bid == 0) {
        int v = (tid < SCAN_BLOCKS) ? part[tid] : 0;
        buf[tid] = v;
        __syncthreads();
        for (int d = 1; d < 256; d <<= 1) {
            int t = (tid >= d) ? buf[tid - d] : 0;
            __syncthreads();
            buf[tid] += t;
            __syncthreads();
        }
        if (tid < SCAN_BLOCKS) part[tid] = buf[tid] - v;
    }
    grid.sync();
    // phase 4: block-local scan + base -> offs; fused dinv
    int v = (i < N_NODES) ? deg[i] : 0;
    buf[tid] = v;
    __syncthreads();
    for (int d = 1; d < 256; d <<= 1) {
        int t = (tid >= d) ? buf[tid - d] : 0;
        __syncthreads();
        buf[tid] += t;
        __syncthreads();
    }
    if (i < N_NODES) {
        int excl = part[bid] + buf[tid] - v;
        offs[i] = excl;
        dinv[i] = rsqrtf((float)v + 1.0f);
        if (i == N_NODES - 1) offs[N_NODES] = part[bid] + buf[tid];  // total == N_EDGES
    }
    grid.sync();
    // phase 5: CSR fill, pure scatter (rank precomputed)
    for (int e = gtid; e < N_EDGES; e += gthreads) {
        int s = ei[e];
        int t = ei[N_EDGES + e];
        srcs[offs[t] + rank[e]] = s;
    }
}

// ---------------- prep: all 3 W's fp32[k][n] -> fp16 transposed [n][k]; zero pooled ----------------
__global__ __launch_bounds__(256) void k_prep(const float* __restrict__ W1, const float* __restrict__ W2,
                                              const float* __restrict__ W3, _Float16* __restrict__ Wt,
                                              float* __restrict__ pooled) {
    int b = blockIdx.x;
    if (b < 192) {
        int idx = b * 256 + threadIdx.x;       // 0..49151
        int l = idx >> 14, r = idx & 16383;
        const float* W = (l == 0) ? W1 : (l == 1) ? W2 : W3;
        int k = r >> 7, n = r & 127;
        Wt[l * 16384 + n * 128 + k] = (_Float16)W[k * 128 + n];
    } else {
        int idx = (b - 192) * 256 + threadIdx.x;
        if (idx < N_GRAPHS * H3) pooled[idx] = 0.0f;
    }
}

// ---------------- T[Mx128](fp8 e4m3) = A[Mx128] @ W (via fp16 MFMA) ----------------
// A is fp32 (layer 1: x) or fp16 (layers 2/3: H). 64 rows/block, 4 waves x 16 rows.
// Operand-swap mfma(b,a,acc): D col(lane&15)=node row, 4 acc regs = 4 consecutive cols.
// Epilogue packs 4 fp32 -> 4 fp8 bytes (one dword store per col-tile).
template <bool A_FP16>
__global__ __launch_bounds__(256) void gemm_mfma(const void* __restrict__ Aptr, const _Float16* __restrict__ Wt,
                                                 unsigned char* __restrict__ T, int M) {
    __shared__ _Float16 As[64 * APAD];    // 17.4 KB
    __shared__ _Float16 Ws[128 * APAD];   // 34.8 KB
    int tid = threadIdx.x;
    int base = blockIdx.x * 64;
    // stage Wt: 128 rows x 16 chunks of 8 f16
    for (int c = tid; c < 2048; c += 256) {
        int n = c >> 4, c8 = (c & 15) << 3;
        *(f16x8*)&Ws[n * APAD + c8] = *(const f16x8*)&Wt[n * 128 + c8];
    }
    // stage A: 64 rows x 16 chunks of 8
    for (int c = tid; c < 1024; c += 256) {
        int r = c >> 4, c8 = (c & 15) << 3;
        int gr = base + r; if (gr >= M) gr = M - 1;
        if (A_FP16) {
            const _Float16* A = (const _Float16*)Aptr;
            *(f16x8*)&As[r * APAD + c8] = *(const f16x8*)&A[(size_t)gr * 128 + c8];
        } else {
            const float* A = (const float*)Aptr;
            const float* src = A + (size_t)gr * 128 + c8;
            float4 v0 = *(const float4*)(src);
            float4 v1 = *(const float4*)(src + 4);
            f16x8 h;
            h[0] = (_Float16)v0.x; h[1] = (_Float16)v0.y; h[2] = (_Float16)v0.z; h[3] = (_Float16)v0.w;
            h[4] = (_Float16)v1.x; h[5] = (_Float16)v1.y; h[6] = (_Float16)v1.z; h[7] = (_Float16)v1.w;
            *(f16x8*)&As[r * APAD + c8] = h;
        }
    }
    __syncthreads();
    int wave = tid >> 6, lane = tid & 63;
    int m = lane & 15, quad = lane >> 4;
    f32x4 acc[8];
#pragma unroll
    for (int ct = 0; ct < 8; ++ct) acc[ct] = (f32x4){0.f, 0.f, 0.f, 0.f};
#pragma unroll
    for (int kc = 0; kc < 4; ++kc) {
        f16x8 a = *(const f16x8*)&As[(wave * 16 + m) * APAD + kc * 32 + quad * 8];
#pragma unroll
        for (int ct = 0; ct < 8; ++ct) {
            f16x8 b = *(const f16x8*)&Ws[(ct * 16 + m) * APAD + kc * 32 + quad * 8];
            acc[ct] = __builtin_amdgcn_mfma_f32_16x16x32_f16(b, a, acc[ct], 0, 0, 0);
        }
    }
    int node = base + wave * 16 + m;
    if (node < M) {
#pragma unroll
        for (int ct = 0; ct < 8; ++ct) {
            int col = ct * 16 + quad * 4;
            int p = __builtin_amdgcn_cvt_pk_fp8_f32(acc[ct][0], acc[ct][1], 0, false);
            p     = __builtin_amdgcn_cvt_pk_fp8_f32(acc[ct][2], acc[ct][3], p, true);
            *(int*)(T + (size_t)node * 128 + col) = p;  // 4B-aligned: col % 4 == 0
        }
    }
}

// ---------------- per-node gather-accumulate: H(fp16) = Ahat * T(fp8) + b ----------------
// 1 wave per node, waves independent. 2 nodes per 128-thread block. Lane reads 2 fp8 dims
// (ushort) and converts via HW v_cvt_pk_f32_fp8. coef recomputed from dinv.
__global__ __launch_bounds__(128) void gather_agg(const unsigned short* __restrict__ T8,
                                                  const int* __restrict__ srcs,
                                                  const int* __restrict__ offs,
                                                  const float* __restrict__ dinv, const float* __restrict__ bias,
                                                  __half2* __restrict__ H2) {
    int node = blockIdx.x * 2 + (threadIdx.x >> 6);
    int lane = threadIdx.x & 63;   // dims 2*lane, 2*lane+1
    if (node >= N_NODES) return;
    float di = dinv[node];
    float2 b2 = *(const float2*)(bias + lane * 2);
    f32x2 sf = __builtin_amdgcn_cvt_pk_f32_fp8((int)T8[(size_t)node * 64 + lane], false);
    float sx = 0.0f, sy = 0.0f;  // edge-sum, weighted by dinv[s] only
    int lo = offs[node], hi = offs[node + 1];
    int e = lo;
    for (; e + 8 <= hi; e += 8) {
        int s0 = srcs[e + 0], s1 = srcs[e + 1], s2 = srcs[e + 2], s3 = srcs[e + 3];
        int s4 = srcs[e + 4], s5 = srcs[e + 5], s6 = srcs[e + 6], s7 = srcs[e + 7];
        float c0 = dinv[s0], c1 = dinv[s1], c2 = dinv[s2], c3 = dinv[s3];
        float c4 = dinv[s4], c5 = dinv[s5], c6 = dinv[s6], c7 = dinv[s7];
        int u0 = T8[(size_t)s0 * 64 + lane];
        int u1 = T8[(size_t)s1 * 64 + lane];
        int u2 = T8[(size_t)s2 * 64 + lane];
        int u3 = T8[(size_t)s3 * 64 + lane];
        int u4 = T8[(size_t)s4 * 64 + lane];
        int u5 = T8[(size_t)s5 * 64 + lane];
        int u6 = T8[(size_t)s6 * 64 + lane];
        int u7 = T8[(size_t)s7 * 64 + lane];
        f32x2 t0 = __builtin_amdgcn_cvt_pk_f32_fp8(u0, false);
        f32x2 t1 = __builtin_amdgcn_cvt_pk_f32_fp8(u1, false);
        f32x2 t2 = __builtin_amdgcn_cvt_pk_f32_fp8(u2, false);
        f32x2 t3 = __builtin_amdgcn_cvt_pk_f32_fp8(u3, false);
        f32x2 t4 = __builtin_amdgcn_cvt_pk_f32_fp8(u4, false);
        f32x2 t5 = __builtin_amdgcn_cvt_pk_f32_fp8(u5, false);
        f32x2 t6 = __builtin_amdgcn_cvt_pk_f32_fp8(u6, false);
        f32x2 t7 = __builtin_amdgcn_cvt_pk_f32_fp8(u7, false);
        sx += t0.x * c0; sy += t0.y * c0;
        sx += t1.x * c1; sy += t1.y * c1;
        sx += t2.x * c2; sy += t2.y * c2;
        sx += t3.x * c3; sy += t3.y * c3;
        sx += t4.x * c4; sy += t4.y * c4;
        sx += t5.x * c5; sy += t5.y * c5;
        sx += t6.x * c6; sy += t6.y * c6;
        sx += t7.x * c7; sy += t7.y * c7;
    }
    for (; e + 4 <= hi; e += 4) {
        int s0 = srcs[e + 0], s1 = srcs[e + 1], s2 = srcs[e + 2], s3 = srcs[e + 3];
        float c0 = dinv[s0], c1 = dinv[s1], c2 = dinv[s2], c3 = dinv[s3];
        f32x2 t0 = __builtin_amdgcn_cvt_pk_f32_fp8((int)T8[(size_t)s0 * 64 + lane], false);
        f32x2 t1 = __builtin_amdgcn_cvt_pk_f32_fp8((int)T8[(size_t)s1 * 64 + lane], false);
        f32x2 t2 = __builtin_amdgcn_cvt_pk_f32_fp8((int)T8[(size_t)s2 * 64 + lane], false);
        f32x2 t3 = __builtin_amdgcn_cvt_pk_f32_fp8((int)T8[(size_t)s3 * 64 + lane], false);
        sx += t0.x * c0; sy += t0.y * c0;
        sx += t1.x * c1; sy += t1.y * c1;
        sx += t2.x * c2; sy += t2.y * c2;
        sx += t3.x * c3; sy += t3.y * c3;
    }
    for (; e < hi; ++e) {
        int s = srcs[e];
        float c = dinv[s];
        f32x2 t = __builtin_amdgcn_cvt_pk_f32_fp8((int)T8[(size_t)s * 64 + lane], false);
        sx += t.x * c; sy += t.y * c;
    }
    float accx = di * sx + sf.x * (di * di) + b2.x;
    float accy = di * sy + sf.y * (di * di) + b2.y;
    H2[(size_t)node * 64 + lane] = __floats2half2_rn(accx, accy);
}

// ---------------- segment-sum pooling, chunked, fp16 H (batch sorted) ----------------
// 256 threads = 4 rows x 64 lane-pairs (__half2 = 2 dims per lane).
__global__ __launch_bounds__(256) void pool_kernel(const __half2* __restrict__ H2, const int* __restrict__ batch,
                                                   float* __restrict__ pooled, int colOff) {
    __shared__ int bounds[2];
    __shared__ float2 red[256];
    int g = blockIdx.x >> 4;        // / POOL_CHUNKS
    int chunk = blockIdx.x & (POOL_CHUNKS - 1);
    int tid = threadIdx.x;
    int d2 = tid & 63, sub = tid >> 6;  // 4 row-accumulators
    if (tid < 2) {
        int target = g + tid;  // lower_bound(batch, target)
        int lo = 0, hi = N_NODES;
        while (lo < hi) {
            int mid = (lo + hi) >> 1;
            if (batch[mid] < target) lo = mid + 1; else hi = mid;
        }
        bounds[tid] = lo;
    }
    __syncthreads();
    int lo = bounds[0], hi = bounds[1];
    int n = hi - lo;
    int per = (n + POOL_CHUNKS - 1) / POOL_CHUNKS;
    int s = lo + chunk * per;
    int e = s + per; if (e > hi) e = hi;
    float ax = 0.0f, ay = 0.0f;
    for (int r = s + sub; r < e; r += 4) {
        float2 v = __half22float2(H2[(size_t)r * 64 + d2]);
        ax += v.x; ay += v.y;
    }
    red[tid] = make_float2(ax, ay);
    __syncthreads();
    if (sub == 0 && s < e) {
        float2 v0 = red[d2], v1 = red[64 + d2], v2 = red[128 + d2], v3 = red[192 + d2];
        float vx = v0.x + v1.x + v2.x + v3.x;
        float vy = v0.y + v1.y + v2.y + v3.y;
        atomicAdd(&pooled[g * H3 + colOff + d2 * 2],     vx);
        atomicAdd(&pooled[g * H3 + colOff + d2 * 2 + 1], vy);
    }
}

// ---------------- MLP head + log_softmax, one block per graph; cnt via binary search ----------------
__global__ __launch_bounds__(384) void mlp_kernel(const float* __restrict__ pooled,
                                                  const int* __restrict__ batch,
                                                  const float* __restrict__ l1W, const float* __restrict__ l1b,
                                                  const float* __restrict__ l2W, const float* __restrict__ l2b,
                                                  float* __restrict__ out) {
    __shared__ float p[H3];
    __shared__ float hid[H3];
    __shared__ float o10[OUTD];
    __shared__ int bnd[2];
    int g = blockIdx.x, tid = threadIdx.x;
    if (tid < 2) {
        int target = g + tid;  // lower_bound(batch, target)
        int lo = 0, hi = N_NODES;
        while (lo < hi) {
            int mid = (lo + hi) >> 1;
            if (batch[mid] < target) lo = mid + 1; else hi = mid;
        }
        bnd[tid] = lo;
    }
    __syncthreads();
    float inv = 1.0f / fmaxf((float)(bnd[1] - bnd[0]), 1.0f);
    p[tid] = pooled[g * H3 + tid] * inv;
    __syncthreads();
    float acc = l1b[tid];
    for (int k = 0; k < H3; ++k) acc += p[k] * l1W[k * H3 + tid];
    hid[tid] = fmaxf(acc, 0.0f);
    __syncthreads();
    if (tid < OUTD) {
        float o = l2b[tid];
        for (int k = 0; k < H3; ++k) o += hid[k] * l2W[k * OUTD + tid];
        o10[tid] = o;
        out[g * OUTD + tid] = o;
    }
    __syncthreads();
    if (tid == 0) {
        float m = o10[0];
        for (int j = 1; j < OUTD; ++j) m = fmaxf(m, o10[j]);
        float s = 0.0f;
        for (int j = 0; j < OUTD; ++j) s += expf(o10[j] - m);
        float lse = m + logf(s);
        for (int j = 0; j < OUTD; ++j) out[N_GRAPHS * OUTD + g * OUTD + j] = o10[j] - lse;
    }
}

extern "C" void kernel_launch(void* const* d_in, const int* in_sizes, int n_in,
                              void* d_out, int out_size, void* d_ws, size_t ws_size,
                              hipStream_t stream) {
    const float* x      = (const float*)d_in[0];
    const float* W1     = (const float*)d_in[1];
    const float* b1     = (const float*)d_in[2];
    const float* W2     = (const float*)d_in[3];
    const float* b2     = (const float*)d_in[4];
    const float* W3     = (const float*)d_in[5];
    const float* b3     = (const float*)d_in[6];
    const float* lin1_W = (const float*)d_in[7];
    const float* lin1_b = (const float*)d_in[8];
    const float* lin2_W = (const float*)d_in[9];
    const float* lin2_b = (const float*)d_in[10];
    const int* edge_index = (const int*)d_in[11];
    const int* batch      = (const int*)d_in[12];

    char* ws = (char*)d_ws;
    auto alloc = [&](size_t bytes) -> void* {
        void* p = (void*)ws;
        ws += (bytes + 255) & ~(size_t)255;
        return p;
    };
    int*   deg    = (int*)  alloc((size_t)N_NODES * 4);
    int*   part   = (int*)  alloc((size_t)SCAN_BLOCKS * 4);
    int*   offs   = (int*)  alloc((size_t)(N_NODES + 1) * 4);
    int*   rank   = (int*)  alloc((size_t)N_EDGES * 4);
    float* dinv   = (float*)alloc((size_t)N_NODES * 4);
    int*   srcs   = (int*)  alloc((size_t)N_EDGES * 4);
    unsigned char* T = (unsigned char*)alloc((size_t)N_NODES * 128);
    __half* H     = (__half*)alloc((size_t)N_NODES * 128 * 2);
    _Float16* Wt  = (_Float16*)alloc((size_t)3 * 128 * 128 * 2);
    float* pooled = (float*)alloc((size_t)N_GRAPHS * H3 * 4);

    // fused preprocessing: one cooperative dispatch replaces 6
    {
        void* args[] = {(void*)&edge_index, (void*)&deg, (void*)&rank, (void*)&part,
                        (void*)&offs, (void*)&dinv, (void*)&srcs};
        hipLaunchCooperativeKernel((const void*)k_graphprep, dim3(SCAN_BLOCKS), dim3(256),
                                   args, 0, stream);
    }
    k_prep<<<288, 256, 0, stream>>>(W1, W2, W3, Wt, pooled);

    const float* bs[3] = {b1, b2, b3};
    for (int l = 0; l < 3; ++l) {
        if (l == 0)
            gemm_mfma<false><<<(N_NODES + 63) / 64, 256, 0, stream>>>(x, Wt, T, N_NODES);
        else
            gemm_mfma<true><<<(N_NODES + 63) / 64, 256, 0, stream>>>(H, Wt + (size_t)l * 16384, T, N_NODES);
        gather_agg<<<(N_NODES + 1) / 2, 128, 0, stream>>>((const unsigned short*)T, srcs, offs, dinv, bs[l], (__half2*)H);
        pool_kernel<<<N_GRAPHS * POOL_CHUNKS, 256, 0, stream>>>((const __half2*)H, batch, pooled, l * 128);
    }
    mlp_kernel<<<N_GRAPHS, 384, 0, stream>>>(pooled, batch, lin1_W, lin1_b, lin2_W, lin2_b, (float*)d_out);
}

// Round 13
// 308.966 us; speedup vs baseline: 1.4118x; 1.4118x over previous
//
#include <hip/hip_runtime.h>
#include <hip/hip_fp16.h>
#include <math.h>

#define N_NODES 50000
#define N_EDGES 600000
#define N_GRAPHS 64
#define DFEAT 128
#define H3 384
#define OUTD 10
#define SCAN_BLOCKS 196   // 196*256 = 50176 >= 50000
#define POOL_CHUNKS 16    // blocks per graph in pooling
#define APAD 136          // fp16 LDS row pad: 272B stride -> conflict-free b128 reads

typedef _Float16 f16x8 __attribute__((ext_vector_type(8)));
typedef float f32x4 __attribute__((ext_vector_type(4)));
typedef float f32x2 __attribute__((ext_vector_type(2)));

// ---------------- degree histogram (in-degree at dst) + per-edge rank ----------------
__global__ __launch_bounds__(256) void k_deg(const int* __restrict__ ei, int* __restrict__ deg,
                                             int* __restrict__ rank) {
    int e = blockIdx.x * 256 + threadIdx.x;
    if (e >= N_EDGES) return;
    int dst = ei[N_EDGES + e];
    rank[e] = atomicAdd(&deg[dst], 1);
}

// ---------------- hierarchical scan, stage 1: per-block partial sums ----------------
__global__ __launch_bounds__(256) void k_part(const int* __restrict__ deg, int* __restrict__ part) {
    __shared__ int red[256];
    int tid = threadIdx.x;
    int i = blockIdx.x * 256 + tid;
    red[tid] = (i < N_NODES) ? deg[i] : 0;
    __syncthreads();
    for (int s = 128; s > 0; s >>= 1) {
        if (tid < s) red[tid] += red[tid + s];
        __syncthreads();
    }
    if (tid == 0) part[blockIdx.x] = red[0];
}

// ---------------- stage 2: one-block scan of the 196 partials -> exclusive bases ----------------
__global__ __launch_bounds__(256) void k_scanpart(const int* __restrict__ part, int* __restrict__ base) {
    __shared__ int buf[256];
    int tid = threadIdx.x;
    int v = (tid < SCAN_BLOCKS) ? part[tid] : 0;
    buf[tid] = v;
    __syncthreads();
    for (int d = 1; d < 256; d <<= 1) {
        int t = (tid >= d) ? buf[tid - d] : 0;
        __syncthreads();
        buf[tid] += t;
        __syncthreads();
    }
    if (tid < SCAN_BLOCKS) base[tid] = buf[tid] - v;  // exclusive
}

// ---------------- stage 3: block-local scan + base -> offs; fused dinv ----------------
__global__ __launch_bounds__(256) void k_offsets(const int* __restrict__ deg, const int* __restrict__ base,
                                                 int* __restrict__ offs, float* __restrict__ dinv) {
    __shared__ int buf[256];
    int tid = threadIdx.x;
    int i = blockIdx.x * 256 + tid;
    int v = (i < N_NODES) ? deg[i] : 0;
    buf[tid] = v;
    __syncthreads();
    for (int d = 1; d < 256; d <<= 1) {
        int t = (tid >= d) ? buf[tid - d] : 0;
        __syncthreads();
        buf[tid] += t;
        __syncthreads();
    }
    if (i < N_NODES) {
        int excl = base[blockIdx.x] + buf[tid] - v;
        offs[i] = excl;
        dinv[i] = rsqrtf((float)v + 1.0f);
        if (i == N_NODES - 1) offs[N_NODES] = base[blockIdx.x] + buf[tid];  // total == N_EDGES
    }
}

// ---------------- fill CSR buckets: packed (src | f16(dinv[src])<<16), no atomics ----------------
__global__ __launch_bounds__(256) void k_fill(const int* __restrict__ ei, const int* __restrict__ offs,
                                              const int* __restrict__ rank, const float* __restrict__ dinv,
                                              unsigned int* __restrict__ epack) {
    int e = blockIdx.x * 256 + threadIdx.x;
    if (e >= N_EDGES) return;
    int s = ei[e];
    int t = ei[N_EDGES + e];
    unsigned short dh = __half_as_ushort(__float2half(dinv[s]));
    epack[offs[t] + rank[e]] = (unsigned int)s | ((unsigned int)dh << 16);  // s < 50000 < 2^16
}

// ---------------- prep: all 3 W's fp32[k][n] -> fp16 transposed [n][k]; zero pooled ----------------
__global__ __launch_bounds__(256) void k_prep(const float* __restrict__ W1, const float* __restrict__ W2,
                                              const float* __restrict__ W3, _Float16* __restrict__ Wt,
                                              float* __restrict__ pooled) {
    int b = blockIdx.x;
    if (b < 192) {
        int idx = b * 256 + threadIdx.x;       // 0..49151
        int l = idx >> 14, r = idx & 16383;
        const float* W = (l == 0) ? W1 : (l == 1) ? W2 : W3;
        int k = r >> 7, n = r & 127;
        Wt[l * 16384 + n * 128 + k] = (_Float16)W[k * 128 + n];
    } else {
        int idx = (b - 192) * 256 + threadIdx.x;
        if (idx < N_GRAPHS * H3) pooled[idx] = 0.0f;
    }
}

// ---------------- T[Mx128](fp8 e4m3) = A[Mx128] @ W (via fp16 MFMA) ----------------
// A is fp32 (layer 1: x) or fp16 (layers 2/3: H). 64 rows/block, 4 waves x 16 rows.
// Operand-swap mfma(b,a,acc): D col(lane&15)=node row, 4 acc regs = 4 consecutive cols.
// Epilogue packs 4 fp32 -> 4 fp8 bytes (one dword store per col-tile).
template <bool A_FP16>
__global__ __launch_bounds__(256) void gemm_mfma(const void* __restrict__ Aptr, const _Float16* __restrict__ Wt,
                                                 unsigned char* __restrict__ T, int M) {
    __shared__ _Float16 As[64 * APAD];    // 17.4 KB
    __shared__ _Float16 Ws[128 * APAD];   // 34.8 KB
    int tid = threadIdx.x;
    int base = blockIdx.x * 64;
    // stage Wt: 128 rows x 16 chunks of 8 f16
    for (int c = tid; c < 2048; c += 256) {
        int n = c >> 4, c8 = (c & 15) << 3;
        *(f16x8*)&Ws[n * APAD + c8] = *(const f16x8*)&Wt[n * 128 + c8];
    }
    // stage A: 64 rows x 16 chunks of 8
    for (int c = tid; c < 1024; c += 256) {
        int r = c >> 4, c8 = (c & 15) << 3;
        int gr = base + r; if (gr >= M) gr = M - 1;
        if (A_FP16) {
            const _Float16* A = (const _Float16*)Aptr;
            *(f16x8*)&As[r * APAD + c8] = *(const f16x8*)&A[(size_t)gr * 128 + c8];
        } else {
            const float* A = (const float*)Aptr;
            const float* src = A + (size_t)gr * 128 + c8;
            float4 v0 = *(const float4*)(src);
            float4 v1 = *(const float4*)(src + 4);
            f16x8 h;
            h[0] = (_Float16)v0.x; h[1] = (_Float16)v0.y; h[2] = (_Float16)v0.z; h[3] = (_Float16)v0.w;
            h[4] = (_Float16)v1.x; h[5] = (_Float16)v1.y; h[6] = (_Float16)v1.z; h[7] = (_Float16)v1.w;
            *(f16x8*)&As[r * APAD + c8] = h;
        }
    }
    __syncthreads();
    int wave = tid >> 6, lane = tid & 63;
    int m = lane & 15, quad = lane >> 4;
    f32x4 acc[8];
#pragma unroll
    for (int ct = 0; ct < 8; ++ct) acc[ct] = (f32x4){0.f, 0.f, 0.f, 0.f};
#pragma unroll
    for (int kc = 0; kc < 4; ++kc) {
        f16x8 a = *(const f16x8*)&As[(wave * 16 + m) * APAD + kc * 32 + quad * 8];
#pragma unroll
        for (int ct = 0; ct < 8; ++ct) {
            f16x8 b = *(const f16x8*)&Ws[(ct * 16 + m) * APAD + kc * 32 + quad * 8];
            acc[ct] = __builtin_amdgcn_mfma_f32_16x16x32_f16(b, a, acc[ct], 0, 0, 0);
        }
    }
    int node = base + wave * 16 + m;
    if (node < M) {
#pragma unroll
        for (int ct = 0; ct < 8; ++ct) {
            int col = ct * 16 + quad * 4;
            int p = __builtin_amdgcn_cvt_pk_fp8_f32(acc[ct][0], acc[ct][1], 0, false);
            p     = __builtin_amdgcn_cvt_pk_fp8_f32(acc[ct][2], acc[ct][3], p, true);
            *(int*)(T + (size_t)node * 128 + col) = p;  // 4B-aligned: col % 4 == 0
        }
    }
}

// ---------------- per-node gather-accumulate: H(fp16) = Ahat * T(fp8) + b ----------------
// 1 wave per node, 2 nodes per 128-thread block. Wave split into two 32-lane halves:
// each half processes alternate edges, each lane loads a uint = 4 fp8 dims (full 128B row
// per half). Cross-half combine via shfl_xor(32). Edge word packs src|f16(dinv[src]).
__global__ __launch_bounds__(128) void gather_agg(const unsigned int* __restrict__ T32,
                                                  const unsigned int* __restrict__ epack,
                                                  const int* __restrict__ offs,
                                                  const float* __restrict__ dinv, const float* __restrict__ bias,
                                                  __half2* __restrict__ H2) {
    int node = blockIdx.x * 2 + (threadIdx.x >> 6);
    int lane = threadIdx.x & 63;
    int half = lane >> 5, l32 = lane & 31;   // dims 4*l32 .. 4*l32+3
    if (node >= N_NODES) return;
    float di = dinv[node];
    float a0 = 0.f, a1 = 0.f, a2 = 0.f, a3 = 0.f;
    int lo = offs[node], hi = offs[node + 1];
    int e = lo + half;
    for (; e + 7 <= hi; e += 8) {   // 4 edges per half per chunk (e, e+2, e+4, e+6)
        unsigned p0 = epack[e + 0], p1 = epack[e + 2], p2 = epack[e + 4], p3 = epack[e + 6];
        int s0 = p0 & 0xffff, s1 = p1 & 0xffff, s2 = p2 & 0xffff, s3 = p3 & 0xffff;
        float c0 = __half2float(__ushort_as_half((unsigned short)(p0 >> 16)));
        float c1 = __half2float(__ushort_as_half((unsigned short)(p1 >> 16)));
        float c2 = __half2float(__ushort_as_half((unsigned short)(p2 >> 16)));
        float c3 = __half2float(__ushort_as_half((unsigned short)(p3 >> 16)));
        unsigned u0 = T32[(size_t)s0 * 32 + l32];
        unsigned u1 = T32[(size_t)s1 * 32 + l32];
        unsigned u2 = T32[(size_t)s2 * 32 + l32];
        unsigned u3 = T32[(size_t)s3 * 32 + l32];
        f32x2 lo0 = __builtin_amdgcn_cvt_pk_f32_fp8(u0, false), hi0 = __builtin_amdgcn_cvt_pk_f32_fp8(u0, true);
        f32x2 lo1 = __builtin_amdgcn_cvt_pk_f32_fp8(u1, false), hi1 = __builtin_amdgcn_cvt_pk_f32_fp8(u1, true);
        f32x2 lo2 = __builtin_amdgcn_cvt_pk_f32_fp8(u2, false), hi2 = __builtin_amdgcn_cvt_pk_f32_fp8(u2, true);
        f32x2 lo3 = __builtin_amdgcn_cvt_pk_f32_fp8(u3, false), hi3 = __builtin_amdgcn_cvt_pk_f32_fp8(u3, true);
        a0 += lo0.x * c0; a1 += lo0.y * c0; a2 += hi0.x * c0; a3 += hi0.y * c0;
        a0 += lo1.x * c1; a1 += lo1.y * c1; a2 += hi1.x * c1; a3 += hi1.y * c1;
        a0 += lo2.x * c2; a1 += lo2.y * c2; a2 += hi2.x * c2; a3 += hi2.y * c2;
        a0 += lo3.x * c3; a1 += lo3.y * c3; a2 += hi3.x * c3; a3 += hi3.y * c3;
    }
    for (; e < hi; e += 2) {
        unsigned p = epack[e];
        int s = p & 0xffff;
        float c = __half2float(__ushort_as_half((unsigned short)(p >> 16)));
        unsigned u = T32[(size_t)s * 32 + l32];
        f32x2 tl = __builtin_amdgcn_cvt_pk_f32_fp8(u, false), th = __builtin_amdgcn_cvt_pk_f32_fp8(u, true);
        a0 += tl.x * c; a1 += tl.y * c; a2 += th.x * c; a3 += th.y * c;
    }
    // cross-half combine (both halves end with the total; only lower half stores)
    a0 += __shfl_xor(a0, 32, 64);
    a1 += __shfl_xor(a1, 32, 64);
    a2 += __shfl_xor(a2, 32, 64);
    a3 += __shfl_xor(a3, 32, 64);
    if (half == 0) {
        unsigned su = T32[(size_t)node * 32 + l32];
        f32x2 sl = __builtin_amdgcn_cvt_pk_f32_fp8(su, false), sh = __builtin_amdgcn_cvt_pk_f32_fp8(su, true);
        float4 b4 = *(const float4*)(bias + l32 * 4);
        float dd = di * di;
        float r0 = di * a0 + sl.x * dd + b4.x;
        float r1 = di * a1 + sl.y * dd + b4.y;
        float r2 = di * a2 + sh.x * dd + b4.z;
        float r3 = di * a3 + sh.y * dd + b4.w;
        H2[(size_t)node * 64 + l32 * 2]     = __floats2half2_rn(r0, r1);
        H2[(size_t)node * 64 + l32 * 2 + 1] = __floats2half2_rn(r2, r3);
    }
}

// ---------------- segment-sum pooling, chunked, fp16 H (batch sorted) ----------------
// 256 threads = 4 rows x 64 lane-pairs (__half2 = 2 dims per lane).
__global__ __launch_bounds__(256) void pool_kernel(const __half2* __restrict__ H2, const int* __restrict__ batch,
                                                   float* __restrict__ pooled, int colOff) {
    __shared__ int bounds[2];
    __shared__ float2 red[256];
    int g = blockIdx.x >> 4;        // / POOL_CHUNKS
    int chunk = blockIdx.x & (POOL_CHUNKS - 1);
    int tid = threadIdx.x;
    int d2 = tid & 63, sub = tid >> 6;  // 4 row-accumulators
    if (tid < 2) {
        int target = g + tid;  // lower_bound(batch, target)
        int lo = 0, hi = N_NODES;
        while (lo < hi) {
            int mid = (lo + hi) >> 1;
            if (batch[mid] < target) lo = mid + 1; else hi = mid;
        }
        bounds[tid] = lo;
    }
    __syncthreads();
    int lo = bounds[0], hi = bounds[1];
    int n = hi - lo;
    int per = (n + POOL_CHUNKS - 1) / POOL_CHUNKS;
    int s = lo + chunk * per;
    int e = s + per; if (e > hi) e = hi;
    float ax = 0.0f, ay = 0.0f;
    for (int r = s + sub; r < e; r += 4) {
        float2 v = __half22float2(H2[(size_t)r * 64 + d2]);
        ax += v.x; ay += v.y;
    }
    red[tid] = make_float2(ax, ay);
    __syncthreads();
    if (sub == 0 && s < e) {
        float2 v0 = red[d2], v1 = red[64 + d2], v2 = red[128 + d2], v3 = red[192 + d2];
        float vx = v0.x + v1.x + v2.x + v3.x;
        float vy = v0.y + v1.y + v2.y + v3.y;
        atomicAdd(&pooled[g * H3 + colOff + d2 * 2],     vx);
        atomicAdd(&pooled[g * H3 + colOff + d2 * 2 + 1], vy);
    }
}

// ---------------- MLP head + log_softmax, one block per graph; cnt via binary search ----------------
__global__ __launch_bounds__(384) void mlp_kernel(const float* __restrict__ pooled,
                                                  const int* __restrict__ batch,
                                                  const float* __restrict__ l1W, const float* __restrict__ l1b,
                                                  const float* __restrict__ l2W, const float* __restrict__ l2b,
                                                  float* __restrict__ out) {
    __shared__ float p[H3];
    __shared__ float hid[H3];
    __shared__ float o10[OUTD];
    __shared__ int bnd[2];
    int g = blockIdx.x, tid = threadIdx.x;
    if (tid < 2) {
        int target = g + tid;  // lower_bound(batch, target)
        int lo = 0, hi = N_NODES;
        while (lo < hi) {
            int mid = (lo + hi) >> 1;
            if (batch[mid] < target) lo = mid + 1; else hi = mid;
        }
        bnd[tid] = lo;
    }
    __syncthreads();
    float inv = 1.0f / fmaxf((float)(bnd[1] - bnd[0]), 1.0f);
    p[tid] = pooled[g * H3 + tid] * inv;
    __syncthreads();
    float acc = l1b[tid];
    for (int k = 0; k < H3; ++k) acc += p[k] * l1W[k * H3 + tid];
    hid[tid] = fmaxf(acc, 0.0f);
    __syncthreads();
    if (tid < OUTD) {
        float o = l2b[tid];
        for (int k = 0; k < H3; ++k) o += hid[k] * l2W[k * OUTD + tid];
        o10[tid] = o;
        out[g * OUTD + tid] = o;
    }
    __syncthreads();
    if (tid == 0) {
        float m = o10[0];
        for (int j = 1; j < OUTD; ++j) m = fmaxf(m, o10[j]);
        float s = 0.0f;
        for (int j = 0; j < OUTD; ++j) s += expf(o10[j] - m);
        float lse = m + logf(s);
        for (int j = 0; j < OUTD; ++j) out[N_GRAPHS * OUTD + g * OUTD + j] = o10[j] - lse;
    }
}

extern "C" void kernel_launch(void* const* d_in, const int* in_sizes, int n_in,
                              void* d_out, int out_size, void* d_ws, size_t ws_size,
                              hipStream_t stream) {
    const float* x      = (const float*)d_in[0];
    const float* W1     = (const float*)d_in[1];
    const float* b1     = (const float*)d_in[2];
    const float* W2     = (const float*)d_in[3];
    const float* b2     = (const float*)d_in[4];
    const float* W3     = (const float*)d_in[5];
    const float* b3     = (const float*)d_in[6];
    const float* lin1_W = (const float*)d_in[7];
    const float* lin1_b = (const float*)d_in[8];
    const float* lin2_W = (const float*)d_in[9];
    const float* lin2_b = (const float*)d_in[10];
    const int* edge_index = (const int*)d_in[11];
    const int* batch      = (const int*)d_in[12];

    char* ws = (char*)d_ws;
    auto alloc = [&](size_t bytes) -> void* {
        void* p = (void*)ws;
        ws += (bytes + 255) & ~(size_t)255;
        return p;
    };
    int*   deg    = (int*)  alloc((size_t)N_NODES * 4);
    int*   part   = (int*)  alloc((size_t)SCAN_BLOCKS * 4);
    int*   pbase  = (int*)  alloc((size_t)SCAN_BLOCKS * 4);
    int*   offs   = (int*)  alloc((size_t)(N_NODES + 1) * 4);
    int*   rank   = (int*)  alloc((size_t)N_EDGES * 4);
    float* dinv   = (float*)alloc((size_t)N_NODES * 4);
    unsigned int* epack = (unsigned int*)alloc((size_t)N_EDGES * 4);
    unsigned char* T = (unsigned char*)alloc((size_t)N_NODES * 128);
    __half* H     = (__half*)alloc((size_t)N_NODES * 128 * 2);
    _Float16* Wt  = (_Float16*)alloc((size_t)3 * 128 * 128 * 2);
    float* pooled = (float*)alloc((size_t)N_GRAPHS * H3 * 4);

    hipMemsetAsync(deg, 0, (size_t)N_NODES * 4, stream);
    k_deg<<<(N_EDGES + 255) / 256, 256, 0, stream>>>(edge_index, deg, rank);
    k_part<<<SCAN_BLOCKS, 256, 0, stream>>>(deg, part);
    k_scanpart<<<1, 256, 0, stream>>>(part, pbase);
    k_offsets<<<SCAN_BLOCKS, 256, 0, stream>>>(deg, pbase, offs, dinv);
    k_fill<<<(N_EDGES + 255) / 256, 256, 0, stream>>>(edge_index, offs, rank, dinv, epack);
    k_prep<<<288, 256, 0, stream>>>(W1, W2, W3, Wt, pooled);

    const float* bs[3] = {b1, b2, b3};
    for (int l = 0; l < 3; ++l) {
        if (l == 0)
            gemm_mfma<false><<<(N_NODES + 63) / 64, 256, 0, stream>>>(x, Wt, T, N_NODES);
        else
            gemm_mfma<true><<<(N_NODES + 63) / 64, 256, 0, stream>>>(H, Wt + (size_t)l * 16384, T, N_NODES);
        gather_agg<<<(N_NODES + 1) / 2, 128, 0, stream>>>((const unsigned int*)T, epack, offs, dinv, bs[l], (__half2*)H);
        pool_kernel<<<N_GRAPHS * POOL_CHUNKS, 256, 0, stream>>>((const __half2*)H, batch, pooled, l * 128);
    }
    mlp_kernel<<<N_GRAPHS, 384, 0, stream>>>(pooled, batch, lin1_W, lin1_b, lin2_W, lin2_b, (float*)d_out);
}

// Round 14
// 296.749 us; speedup vs baseline: 1.4699x; 1.0412x over previous
//
#include <hip/hip_runtime.h>
#include <hip/hip_fp16.h>
#include <math.h>

#define N_NODES 50000
#define N_EDGES 600000
#define N_GRAPHS 64
#define DFEAT 128
#define H3 384
#define OUTD 10
#define SCAN_BLOCKS 196   // 196*256 = 50176 >= 50000
#define POOL_CHUNKS 16    // blocks per graph in pooling
#define APAD 136          // fp16 LDS row pad: 272B stride -> conflict-free b128 reads

typedef _Float16 f16x8 __attribute__((ext_vector_type(8)));
typedef float f32x4 __attribute__((ext_vector_type(4)));
typedef float f32x2 __attribute__((ext_vector_type(2)));

// ---------------- degree histogram (in-degree at dst) + per-edge rank ----------------
__global__ __launch_bounds__(256) void k_deg(const int* __restrict__ ei, int* __restrict__ deg,
                                             int* __restrict__ rank) {
    int e = blockIdx.x * 256 + threadIdx.x;
    if (e >= N_EDGES) return;
    int dst = ei[N_EDGES + e];
    rank[e] = atomicAdd(&deg[dst], 1);
}

// ---------------- hierarchical scan, stage 1: per-block partial sums ----------------
__global__ __launch_bounds__(256) void k_part(const int* __restrict__ deg, int* __restrict__ part) {
    __shared__ int red[256];
    int tid = threadIdx.x;
    int i = blockIdx.x * 256 + tid;
    red[tid] = (i < N_NODES) ? deg[i] : 0;
    __syncthreads();
    for (int s = 128; s > 0; s >>= 1) {
        if (tid < s) red[tid] += red[tid + s];
        __syncthreads();
    }
    if (tid == 0) part[blockIdx.x] = red[0];
}

// ---------------- stage 2: one-block scan of the 196 partials -> exclusive bases ----------------
__global__ __launch_bounds__(256) void k_scanpart(const int* __restrict__ part, int* __restrict__ base) {
    __shared__ int buf[256];
    int tid = threadIdx.x;
    int v = (tid < SCAN_BLOCKS) ? part[tid] : 0;
    buf[tid] = v;
    __syncthreads();
    for (int d = 1; d < 256; d <<= 1) {
        int t = (tid >= d) ? buf[tid - d] : 0;
        __syncthreads();
        buf[tid] += t;
        __syncthreads();
    }
    if (tid < SCAN_BLOCKS) base[tid] = buf[tid] - v;  // exclusive
}

// ---------------- stage 3: block-local scan + base -> offs; fused dinv ----------------
__global__ __launch_bounds__(256) void k_offsets(const int* __restrict__ deg, const int* __restrict__ base,
                                                 int* __restrict__ offs, float* __restrict__ dinv) {
    __shared__ int buf[256];
    int tid = threadIdx.x;
    int i = blockIdx.x * 256 + tid;
    int v = (i < N_NODES) ? deg[i] : 0;
    buf[tid] = v;
    __syncthreads();
    for (int d = 1; d < 256; d <<= 1) {
        int t = (tid >= d) ? buf[tid - d] : 0;
        __syncthreads();
        buf[tid] += t;
        __syncthreads();
    }
    if (i < N_NODES) {
        int excl = base[blockIdx.x] + buf[tid] - v;
        offs[i] = excl;
        dinv[i] = rsqrtf((float)v + 1.0f);
        if (i == N_NODES - 1) offs[N_NODES] = base[blockIdx.x] + buf[tid];  // total == N_EDGES
    }
}

// ---------------- fill CSR buckets: packed (src | f16(dinv[src])<<16), no atomics ----------------
__global__ __launch_bounds__(256) void k_fill(const int* __restrict__ ei, const int* __restrict__ offs,
                                              const int* __restrict__ rank, const float* __restrict__ dinv,
                                              unsigned int* __restrict__ epack) {
    int e = blockIdx.x * 256 + threadIdx.x;
    if (e >= N_EDGES) return;
    int s = ei[e];
    int t = ei[N_EDGES + e];
    unsigned short dh = __half_as_ushort(__float2half(dinv[s]));
    epack[offs[t] + rank[e]] = (unsigned int)s | ((unsigned int)dh << 16);  // s < 50000 < 2^16
}

// ---------------- prep: all 3 W's fp32[k][n] -> fp16 transposed [n][k]; zero pooled ----------------
__global__ __launch_bounds__(256) void k_prep(const float* __restrict__ W1, const float* __restrict__ W2,
                                              const float* __restrict__ W3, _Float16* __restrict__ Wt,
                                              float* __restrict__ pooled) {
    int b = blockIdx.x;
    if (b < 192) {
        int idx = b * 256 + threadIdx.x;       // 0..49151
        int l = idx >> 14, r = idx & 16383;
        const float* W = (l == 0) ? W1 : (l == 1) ? W2 : W3;
        int k = r >> 7, n = r & 127;
        Wt[l * 16384 + n * 128 + k] = (_Float16)W[k * 128 + n];
    } else {
        int idx = (b - 192) * 256 + threadIdx.x;
        if (idx < N_GRAPHS * H3) pooled[idx] = 0.0f;
    }
}

// ---------------- T[Mx128](fp8 e4m3) = A[Mx128] @ W (via fp16 MFMA) ----------------
// A is fp32 (layer 1: x) or fp16 (layers 2/3: H). 64 rows/block, 4 waves x 16 rows.
// Operand-swap mfma(b,a,acc): D col(lane&15)=node row, 4 acc regs = 4 consecutive cols.
// Epilogue packs 4 fp32 -> 4 fp8 bytes (one dword store per col-tile).
template <bool A_FP16>
__global__ __launch_bounds__(256) void gemm_mfma(const void* __restrict__ Aptr, const _Float16* __restrict__ Wt,
                                                 unsigned char* __restrict__ T, int M) {
    __shared__ _Float16 As[64 * APAD];    // 17.4 KB
    __shared__ _Float16 Ws[128 * APAD];   // 34.8 KB
    int tid = threadIdx.x;
    int base = blockIdx.x * 64;
    // stage Wt: 128 rows x 16 chunks of 8 f16
    for (int c = tid; c < 2048; c += 256) {
        int n = c >> 4, c8 = (c & 15) << 3;
        *(f16x8*)&Ws[n * APAD + c8] = *(const f16x8*)&Wt[n * 128 + c8];
    }
    // stage A: 64 rows x 16 chunks of 8
    for (int c = tid; c < 1024; c += 256) {
        int r = c >> 4, c8 = (c & 15) << 3;
        int gr = base + r; if (gr >= M) gr = M - 1;
        if (A_FP16) {
            const _Float16* A = (const _Float16*)Aptr;
            *(f16x8*)&As[r * APAD + c8] = *(const f16x8*)&A[(size_t)gr * 128 + c8];
        } else {
            const float* A = (const float*)Aptr;
            const float* src = A + (size_t)gr * 128 + c8;
            float4 v0 = *(const float4*)(src);
            float4 v1 = *(const float4*)(src + 4);
            f16x8 h;
            h[0] = (_Float16)v0.x; h[1] = (_Float16)v0.y; h[2] = (_Float16)v0.z; h[3] = (_Float16)v0.w;
            h[4] = (_Float16)v1.x; h[5] = (_Float16)v1.y; h[6] = (_Float16)v1.z; h[7] = (_Float16)v1.w;
            *(f16x8*)&As[r * APAD + c8] = h;
        }
    }
    __syncthreads();
    int wave = tid >> 6, lane = tid & 63;
    int m = lane & 15, quad = lane >> 4;
    f32x4 acc[8];
#pragma unroll
    for (int ct = 0; ct < 8; ++ct) acc[ct] = (f32x4){0.f, 0.f, 0.f, 0.f};
#pragma unroll
    for (int kc = 0; kc < 4; ++kc) {
        f16x8 a = *(const f16x8*)&As[(wave * 16 + m) * APAD + kc * 32 + quad * 8];
#pragma unroll
        for (int ct = 0; ct < 8; ++ct) {
            f16x8 b = *(const f16x8*)&Ws[(ct * 16 + m) * APAD + kc * 32 + quad * 8];
            acc[ct] = __builtin_amdgcn_mfma_f32_16x16x32_f16(b, a, acc[ct], 0, 0, 0);
        }
    }
    int node = base + wave * 16 + m;
    if (node < M) {
#pragma unroll
        for (int ct = 0; ct < 8; ++ct) {
            int col = ct * 16 + quad * 4;
            int p = __builtin_amdgcn_cvt_pk_fp8_f32(acc[ct][0], acc[ct][1], 0, false);
            p     = __builtin_amdgcn_cvt_pk_fp8_f32(acc[ct][2], acc[ct][3], p, true);
            *(int*)(T + (size_t)node * 128 + col) = p;  // 4B-aligned: col % 4 == 0
        }
    }
}

// ---------------- per-node gather-accumulate: H(fp16) = Ahat * T(fp8) + b ----------------
// One node per 32-lane half-wave (independent halves, no combine): lane loads a uint =
// 4 fp8 dims, 32 lanes = full 128B row. One vmem instr per wave-iter serves 2 nodes.
// 4 nodes per 128-thread block; epack reads are consecutive (uniform per half).
__global__ __launch_bounds__(128) void gather_agg(const unsigned int* __restrict__ T32,
                                                  const unsigned int* __restrict__ epack,
                                                  const int* __restrict__ offs,
                                                  const float* __restrict__ dinv, const float* __restrict__ bias,
                                                  __half2* __restrict__ H2) {
    int h = threadIdx.x >> 5;        // half-wave 0..3
    int l32 = threadIdx.x & 31;      // dims 4*l32 .. 4*l32+3
    int node = blockIdx.x * 4 + h;   // grid = 12500, exact
    float di = dinv[node];
    float a0 = 0.f, a1 = 0.f, a2 = 0.f, a3 = 0.f;
    int lo = offs[node], hi = offs[node + 1];
    int e = lo;
    for (; e + 8 <= hi; e += 8) {
        unsigned p0 = epack[e + 0], p1 = epack[e + 1], p2 = epack[e + 2], p3 = epack[e + 3];
        unsigned p4 = epack[e + 4], p5 = epack[e + 5], p6 = epack[e + 6], p7 = epack[e + 7];
        unsigned u0 = T32[(size_t)(p0 & 0xffff) * 32 + l32];
        unsigned u1 = T32[(size_t)(p1 & 0xffff) * 32 + l32];
        unsigned u2 = T32[(size_t)(p2 & 0xffff) * 32 + l32];
        unsigned u3 = T32[(size_t)(p3 & 0xffff) * 32 + l32];
        unsigned u4 = T32[(size_t)(p4 & 0xffff) * 32 + l32];
        unsigned u5 = T32[(size_t)(p5 & 0xffff) * 32 + l32];
        unsigned u6 = T32[(size_t)(p6 & 0xffff) * 32 + l32];
        unsigned u7 = T32[(size_t)(p7 & 0xffff) * 32 + l32];
        float c0 = __half2float(__ushort_as_half((unsigned short)(p0 >> 16)));
        float c1 = __half2float(__ushort_as_half((unsigned short)(p1 >> 16)));
        float c2 = __half2float(__ushort_as_half((unsigned short)(p2 >> 16)));
        float c3 = __half2float(__ushort_as_half((unsigned short)(p3 >> 16)));
        float c4 = __half2float(__ushort_as_half((unsigned short)(p4 >> 16)));
        float c5 = __half2float(__ushort_as_half((unsigned short)(p5 >> 16)));
        float c6 = __half2float(__ushort_as_half((unsigned short)(p6 >> 16)));
        float c7 = __half2float(__ushort_as_half((unsigned short)(p7 >> 16)));
        f32x2 lo0 = __builtin_amdgcn_cvt_pk_f32_fp8(u0, false), hi0 = __builtin_amdgcn_cvt_pk_f32_fp8(u0, true);
        f32x2 lo1 = __builtin_amdgcn_cvt_pk_f32_fp8(u1, false), hi1 = __builtin_amdgcn_cvt_pk_f32_fp8(u1, true);
        f32x2 lo2 = __builtin_amdgcn_cvt_pk_f32_fp8(u2, false), hi2 = __builtin_amdgcn_cvt_pk_f32_fp8(u2, true);
        f32x2 lo3 = __builtin_amdgcn_cvt_pk_f32_fp8(u3, false), hi3 = __builtin_amdgcn_cvt_pk_f32_fp8(u3, true);
        f32x2 lo4 = __builtin_amdgcn_cvt_pk_f32_fp8(u4, false), hi4 = __builtin_amdgcn_cvt_pk_f32_fp8(u4, true);
        f32x2 lo5 = __builtin_amdgcn_cvt_pk_f32_fp8(u5, false), hi5 = __builtin_amdgcn_cvt_pk_f32_fp8(u5, true);
        f32x2 lo6 = __builtin_amdgcn_cvt_pk_f32_fp8(u6, false), hi6 = __builtin_amdgcn_cvt_pk_f32_fp8(u6, true);
        f32x2 lo7 = __builtin_amdgcn_cvt_pk_f32_fp8(u7, false), hi7 = __builtin_amdgcn_cvt_pk_f32_fp8(u7, true);
        a0 += lo0.x * c0; a1 += lo0.y * c0; a2 += hi0.x * c0; a3 += hi0.y * c0;
        a0 += lo1.x * c1; a1 += lo1.y * c1; a2 += hi1.x * c1; a3 += hi1.y * c1;
        a0 += lo2.x * c2; a1 += lo2.y * c2; a2 += hi2.x * c2; a3 += hi2.y * c2;
        a0 += lo3.x * c3; a1 += lo3.y * c3; a2 += hi3.x * c3; a3 += hi3.y * c3;
        a0 += lo4.x * c4; a1 += lo4.y * c4; a2 += hi4.x * c4; a3 += hi4.y * c4;
        a0 += lo5.x * c5; a1 += lo5.y * c5; a2 += hi5.x * c5; a3 += hi5.y * c5;
        a0 += lo6.x * c6; a1 += lo6.y * c6; a2 += hi6.x * c6; a3 += hi6.y * c6;
        a0 += lo7.x * c7; a1 += lo7.y * c7; a2 += hi7.x * c7; a3 += hi7.y * c7;
    }
    for (; e < hi; ++e) {
        unsigned p = epack[e];
        float c = __half2float(__ushort_as_half((unsigned short)(p >> 16)));
        unsigned u = T32[(size_t)(p & 0xffff) * 32 + l32];
        f32x2 tl = __builtin_amdgcn_cvt_pk_f32_fp8(u, false), th = __builtin_amdgcn_cvt_pk_f32_fp8(u, true);
        a0 += tl.x * c; a1 += tl.y * c; a2 += th.x * c; a3 += th.y * c;
    }
    unsigned su = T32[(size_t)node * 32 + l32];
    f32x2 sl = __builtin_amdgcn_cvt_pk_f32_fp8(su, false), sh = __builtin_amdgcn_cvt_pk_f32_fp8(su, true);
    float4 b4 = *(const float4*)(bias + l32 * 4);
    float dd = di * di;
    float r0 = di * a0 + sl.x * dd + b4.x;
    float r1 = di * a1 + sl.y * dd + b4.y;
    float r2 = di * a2 + sh.x * dd + b4.z;
    float r3 = di * a3 + sh.y * dd + b4.w;
    H2[(size_t)node * 64 + l32 * 2]     = __floats2half2_rn(r0, r1);
    H2[(size_t)node * 64 + l32 * 2 + 1] = __floats2half2_rn(r2, r3);
}

// ---------------- segment-sum pooling, all 3 layers in one dispatch ----------------
// grid = 64 graphs x 16 chunks, 256 threads = 4 rows x 64 lane-pairs. Bounds search once.
__global__ __launch_bounds__(256) void pool_kernel(const __half2* __restrict__ H0,
                                                   const __half2* __restrict__ H1,
                                                   const __half2* __restrict__ H2buf,
                                                   const int* __restrict__ batch,
                                                   float* __restrict__ pooled) {
    __shared__ int bounds[2];
    __shared__ float2 red[256];
    int g = blockIdx.x >> 4;        // / POOL_CHUNKS
    int chunk = blockIdx.x & (POOL_CHUNKS - 1);
    int tid = threadIdx.x;
    int d2 = tid & 63, sub = tid >> 6;  // 4 row-accumulators
    if (tid < 2) {
        int target = g + tid;  // lower_bound(batch, target)
        int lo = 0, hi = N_NODES;
        while (lo < hi) {
            int mid = (lo + hi) >> 1;
            if (batch[mid] < target) lo = mid + 1; else hi = mid;
        }
        bounds[tid] = lo;
    }
    __syncthreads();
    int lo = bounds[0], hi = bounds[1];
    int n = hi - lo;
    int per = (n + POOL_CHUNKS - 1) / POOL_CHUNKS;
    int s = lo + chunk * per;
    int e = s + per; if (e > hi) e = hi;
    const __half2* Hs[3] = {H0, H1, H2buf};
    for (int l = 0; l < 3; ++l) {
        const __half2* H = Hs[l];
        float ax = 0.0f, ay = 0.0f;
        for (int r = s + sub; r < e; r += 4) {
            float2 v = __half22float2(H[(size_t)r * 64 + d2]);
            ax += v.x; ay += v.y;
        }
        red[tid] = make_float2(ax, ay);
        __syncthreads();
        if (sub == 0 && s < e) {
            float2 v0 = red[d2], v1 = red[64 + d2], v2 = red[128 + d2], v3 = red[192 + d2];
            atomicAdd(&pooled[g * H3 + l * 128 + d2 * 2],     v0.x + v1.x + v2.x + v3.x);
            atomicAdd(&pooled[g * H3 + l * 128 + d2 * 2 + 1], v0.y + v1.y + v2.y + v3.y);
        }
        __syncthreads();
    }
}

// ---------------- MLP head + log_softmax, one block per graph; cnt via binary search ----------------
__global__ __launch_bounds__(384) void mlp_kernel(const float* __restrict__ pooled,
                                                  const int* __restrict__ batch,
                                                  const float* __restrict__ l1W, const float* __restrict__ l1b,
                                                  const float* __restrict__ l2W, const float* __restrict__ l2b,
                                                  float* __restrict__ out) {
    __shared__ float p[H3];
    __shared__ float hid[H3];
    __shared__ float o10[OUTD];
    __shared__ int bnd[2];
    int g = blockIdx.x, tid = threadIdx.x;
    if (tid < 2) {
        int target = g + tid;  // lower_bound(batch, target)
        int lo = 0, hi = N_NODES;
        while (lo < hi) {
            int mid = (lo + hi) >> 1;
            if (batch[mid] < target) lo = mid + 1; else hi = mid;
        }
        bnd[tid] = lo;
    }
    __syncthreads();
    float inv = 1.0f / fmaxf((float)(bnd[1] - bnd[0]), 1.0f);
    p[tid] = pooled[g * H3 + tid] * inv;
    __syncthreads();
    float acc = l1b[tid];
    for (int k = 0; k < H3; ++k) acc += p[k] * l1W[k * H3 + tid];
    hid[tid] = fmaxf(acc, 0.0f);
    __syncthreads();
    if (tid < OUTD) {
        float o = l2b[tid];
        for (int k = 0; k < H3; ++k) o += hid[k] * l2W[k * OUTD + tid];
        o10[tid] = o;
        out[g * OUTD + tid] = o;
    }
    __syncthreads();
    if (tid == 0) {
        float m = o10[0];
        for (int j = 1; j < OUTD; ++j) m = fmaxf(m, o10[j]);
        float s = 0.0f;
        for (int j = 0; j < OUTD; ++j) s += expf(o10[j] - m);
        float lse = m + logf(s);
        for (int j = 0; j < OUTD; ++j) out[N_GRAPHS * OUTD + g * OUTD + j] = o10[j] - lse;
    }
}

extern "C" void kernel_launch(void* const* d_in, const int* in_sizes, int n_in,
                              void* d_out, int out_size, void* d_ws, size_t ws_size,
                              hipStream_t stream) {
    const float* x      = (const float*)d_in[0];
    const float* W1     = (const float*)d_in[1];
    const float* b1     = (const float*)d_in[2];
    const float* W2     = (const float*)d_in[3];
    const float* b2     = (const float*)d_in[4];
    const float* W3     = (const float*)d_in[5];
    const float* b3     = (const float*)d_in[6];
    const float* lin1_W = (const float*)d_in[7];
    const float* lin1_b = (const float*)d_in[8];
    const float* lin2_W = (const float*)d_in[9];
    const float* lin2_b = (const float*)d_in[10];
    const int* edge_index = (const int*)d_in[11];
    const int* batch      = (const int*)d_in[12];

    char* ws = (char*)d_ws;
    auto alloc = [&](size_t bytes) -> void* {
        void* p = (void*)ws;
        ws += (bytes + 255) & ~(size_t)255;
        return p;
    };
    int*   deg    = (int*)  alloc((size_t)N_NODES * 4);
    int*   part   = (int*)  alloc((size_t)SCAN_BLOCKS * 4);
    int*   pbase  = (int*)  alloc((size_t)SCAN_BLOCKS * 4);
    int*   offs   = (int*)  alloc((size_t)(N_NODES + 1) * 4);
    int*   rank   = (int*)  alloc((size_t)N_EDGES * 4);
    float* dinv   = (float*)alloc((size_t)N_NODES * 4);
    unsigned int* epack = (unsigned int*)alloc((size_t)N_EDGES * 4);
    unsigned char* T = (unsigned char*)alloc((size_t)N_NODES * 128);
    __half* Hbuf[3];
    for (int l = 0; l < 3; ++l) Hbuf[l] = (__half*)alloc((size_t)N_NODES * 128 * 2);
    _Float16* Wt  = (_Float16*)alloc((size_t)3 * 128 * 128 * 2);
    float* pooled = (float*)alloc((size_t)N_GRAPHS * H3 * 4);

    hipMemsetAsync(deg, 0, (size_t)N_NODES * 4, stream);
    k_deg<<<(N_EDGES + 255) / 256, 256, 0, stream>>>(edge_index, deg, rank);
    k_part<<<SCAN_BLOCKS, 256, 0, stream>>>(deg, part);
    k_scanpart<<<1, 256, 0, stream>>>(part, pbase);
    k_offsets<<<SCAN_BLOCKS, 256, 0, stream>>>(deg, pbase, offs, dinv);
    k_fill<<<(N_EDGES + 255) / 256, 256, 0, stream>>>(edge_index, offs, rank, dinv, epack);
    k_prep<<<288, 256, 0, stream>>>(W1, W2, W3, Wt, pooled);

    const float* bs[3] = {b1, b2, b3};
    for (int l = 0; l < 3; ++l) {
        if (l == 0)
            gemm_mfma<false><<<(N_NODES + 63) / 64, 256, 0, stream>>>(x, Wt, T, N_NODES);
        else
            gemm_mfma<true><<<(N_NODES + 63) / 64, 256, 0, stream>>>(Hbuf[l - 1], Wt + (size_t)l * 16384, T, N_NODES);
        gather_agg<<<N_NODES / 4, 128, 0, stream>>>((const unsigned int*)T, epack, offs, dinv, bs[l], (__half2*)Hbuf[l]);
    }
    pool_kernel<<<N_GRAPHS * POOL_CHUNKS, 256, 0, stream>>>((const __half2*)Hbuf[0], (const __half2*)Hbuf[1],
                                                            (const __half2*)Hbuf[2], batch, pooled);
    mlp_kernel<<<N_GRAPHS, 384, 0, stream>>>(pooled, batch, lin1_W, lin1_b, lin2_W, lin2_b, (float*)d_out);
}

// Round 15
// 284.016 us; speedup vs baseline: 1.5358x; 1.0448x over previous
//
#include <hip/hip_runtime.h>
#include <hip/hip_fp16.h>
#include <math.h>

#define N_NODES 50000
#define N_EDGES 600000
#define N_GRAPHS 64
#define DFEAT 128
#define H3 384
#define OUTD 10
#define SCAN_BLOCKS 196   // 196*256 = 50176 >= 50000
#define POOL_CHUNKS 16    // blocks per graph in pooling
#define APAD 136          // fp16 LDS row pad: 272B stride -> conflict-free b128 reads

typedef _Float16 f16x8 __attribute__((ext_vector_type(8)));
typedef float f32x4 __attribute__((ext_vector_type(4)));
typedef float f32x2 __attribute__((ext_vector_type(2)));

// ---------------- degree histogram (in-degree at dst) + per-edge rank ----------------
__global__ __launch_bounds__(256) void k_deg(const int* __restrict__ ei, int* __restrict__ deg,
                                             int* __restrict__ rank) {
    int e = blockIdx.x * 256 + threadIdx.x;
    if (e >= N_EDGES) return;
    int dst = ei[N_EDGES + e];
    rank[e] = atomicAdd(&deg[dst], 1);
}

// ---------------- hierarchical scan, stage 1: per-block partial sums ----------------
__global__ __launch_bounds__(256) void k_part(const int* __restrict__ deg, int* __restrict__ part) {
    __shared__ int red[256];
    int tid = threadIdx.x;
    int i = blockIdx.x * 256 + tid;
    red[tid] = (i < N_NODES) ? deg[i] : 0;
    __syncthreads();
    for (int s = 128; s > 0; s >>= 1) {
        if (tid < s) red[tid] += red[tid + s];
        __syncthreads();
    }
    if (tid == 0) part[blockIdx.x] = red[0];
}

// ---------------- stage 2: one-block scan of the 196 partials -> exclusive bases ----------------
__global__ __launch_bounds__(256) void k_scanpart(const int* __restrict__ part, int* __restrict__ base) {
    __shared__ int buf[256];
    int tid = threadIdx.x;
    int v = (tid < SCAN_BLOCKS) ? part[tid] : 0;
    buf[tid] = v;
    __syncthreads();
    for (int d = 1; d < 256; d <<= 1) {
        int t = (tid >= d) ? buf[tid - d] : 0;
        __syncthreads();
        buf[tid] += t;
        __syncthreads();
    }
    if (tid < SCAN_BLOCKS) base[tid] = buf[tid] - v;  // exclusive
}

// ---------------- stage 3: block-local scan + base -> offs; fused dinv ----------------
__global__ __launch_bounds__(256) void k_offsets(const int* __restrict__ deg, const int* __restrict__ base,
                                                 int* __restrict__ offs, float* __restrict__ dinv) {
    __shared__ int buf[256];
    int tid = threadIdx.x;
    int i = blockIdx.x * 256 + tid;
    int v = (i < N_NODES) ? deg[i] : 0;
    buf[tid] = v;
    __syncthreads();
    for (int d = 1; d < 256; d <<= 1) {
        int t = (tid >= d) ? buf[tid - d] : 0;
        __syncthreads();
        buf[tid] += t;
        __syncthreads();
    }
    if (i < N_NODES) {
        int excl = base[blockIdx.x] + buf[tid] - v;
        offs[i] = excl;
        dinv[i] = rsqrtf((float)v + 1.0f);
        if (i == N_NODES - 1) offs[N_NODES] = base[blockIdx.x] + buf[tid];  // total == N_EDGES
    }
}

// ---------------- fill CSR buckets: packed (src | f16(dinv[src])<<16), no atomics ----------------
__global__ __launch_bounds__(256) void k_fill(const int* __restrict__ ei, const int* __restrict__ offs,
                                              const int* __restrict__ rank, const float* __restrict__ dinv,
                                              unsigned int* __restrict__ epack) {
    int e = blockIdx.x * 256 + threadIdx.x;
    if (e >= N_EDGES) return;
    int s = ei[e];
    int t = ei[N_EDGES + e];
    unsigned short dh = __half_as_ushort(__float2half(dinv[s]));
    epack[offs[t] + rank[e]] = (unsigned int)s | ((unsigned int)dh << 16);  // s < 50000 < 2^16
}

// ---------------- prep: all 3 W's fp32[k][n] -> fp16 transposed [n][k]; zero pooled ----------------
__global__ __launch_bounds__(256) void k_prep(const float* __restrict__ W1, const float* __restrict__ W2,
                                              const float* __restrict__ W3, _Float16* __restrict__ Wt,
                                              float* __restrict__ pooled) {
    int b = blockIdx.x;
    if (b < 192) {
        int idx = b * 256 + threadIdx.x;       // 0..49151
        int l = idx >> 14, r = idx & 16383;
        const float* W = (l == 0) ? W1 : (l == 1) ? W2 : W3;
        int k = r >> 7, n = r & 127;
        Wt[l * 16384 + n * 128 + k] = (_Float16)W[k * 128 + n];
    } else {
        int idx = (b - 192) * 256 + threadIdx.x;
        if (idx < N_GRAPHS * H3) pooled[idx] = 0.0f;
    }
}

// ---------------- T[Mx128](fp8 e4m3) = A[Mx128] @ W (via fp16 MFMA) ----------------
// A is fp32 (layer 1: x) or fp16 (layers 2/3: H). 64 rows/block, 4 waves x 16 rows.
// Operand-swap mfma(b,a,acc): D col(lane&15)=node row, 4 acc regs = 4 consecutive cols.
// Epilogue packs 4 fp32 -> 4 fp8 bytes (one dword store per col-tile).
template <bool A_FP16>
__global__ __launch_bounds__(256) void gemm_mfma(const void* __restrict__ Aptr, const _Float16* __restrict__ Wt,
                                                 unsigned char* __restrict__ T, int M) {
    __shared__ _Float16 As[64 * APAD];    // 17.4 KB
    __shared__ _Float16 Ws[128 * APAD];   // 34.8 KB
    int tid = threadIdx.x;
    int base = blockIdx.x * 64;
    // stage Wt: 128 rows x 16 chunks of 8 f16
    for (int c = tid; c < 2048; c += 256) {
        int n = c >> 4, c8 = (c & 15) << 3;
        *(f16x8*)&Ws[n * APAD + c8] = *(const f16x8*)&Wt[n * 128 + c8];
    }
    // stage A: 64 rows x 16 chunks of 8
    for (int c = tid; c < 1024; c += 256) {
        int r = c >> 4, c8 = (c & 15) << 3;
        int gr = base + r; if (gr >= M) gr = M - 1;
        if (A_FP16) {
            const _Float16* A = (const _Float16*)Aptr;
            *(f16x8*)&As[r * APAD + c8] = *(const f16x8*)&A[(size_t)gr * 128 + c8];
        } else {
            const float* A = (const float*)Aptr;
            const float* src = A + (size_t)gr * 128 + c8;
            float4 v0 = *(const float4*)(src);
            float4 v1 = *(const float4*)(src + 4);
            f16x8 h;
            h[0] = (_Float16)v0.x; h[1] = (_Float16)v0.y; h[2] = (_Float16)v0.z; h[3] = (_Float16)v0.w;
            h[4] = (_Float16)v1.x; h[5] = (_Float16)v1.y; h[6] = (_Float16)v1.z; h[7] = (_Float16)v1.w;
            *(f16x8*)&As[r * APAD + c8] = h;
        }
    }
    __syncthreads();
    int wave = tid >> 6, lane = tid & 63;
    int m = lane & 15, quad = lane >> 4;
    f32x4 acc[8];
#pragma unroll
    for (int ct = 0; ct < 8; ++ct) acc[ct] = (f32x4){0.f, 0.f, 0.f, 0.f};
#pragma unroll
    for (int kc = 0; kc < 4; ++kc) {
        f16x8 a = *(const f16x8*)&As[(wave * 16 + m) * APAD + kc * 32 + quad * 8];
#pragma unroll
        for (int ct = 0; ct < 8; ++ct) {
            f16x8 b = *(const f16x8*)&Ws[(ct * 16 + m) * APAD + kc * 32 + quad * 8];
            acc[ct] = __builtin_amdgcn_mfma_f32_16x16x32_f16(b, a, acc[ct], 0, 0, 0);
        }
    }
    int node = base + wave * 16 + m;
    if (node < M) {
#pragma unroll
        for (int ct = 0; ct < 8; ++ct) {
            int col = ct * 16 + quad * 4;
            int p = __builtin_amdgcn_cvt_pk_fp8_f32(acc[ct][0], acc[ct][1], 0, false);
            p     = __builtin_amdgcn_cvt_pk_fp8_f32(acc[ct][2], acc[ct][3], p, true);
            *(int*)(T + (size_t)node * 128 + col) = p;  // 4B-aligned: col % 4 == 0
        }
    }
}

// ---------------- per-node gather-accumulate: H(fp16) = Ahat * T(fp8) + b ----------------
// One node per 32-lane half-wave (independent halves): lane loads a uint = 4 fp8 dims,
// 32 lanes = full 128B row. 8 nodes per 256-thread block (grid 6250 exact).
// 8-deep main unroll + 4-deep remainder keep >=4 row loads in flight through the tail.
__global__ __launch_bounds__(256) void gather_agg(const unsigned int* __restrict__ T32,
                                                  const unsigned int* __restrict__ epack,
                                                  const int* __restrict__ offs,
                                                  const float* __restrict__ dinv, const float* __restrict__ bias,
                                                  __half2* __restrict__ H2) {
    int h = threadIdx.x >> 5;        // half-wave 0..7
    int l32 = threadIdx.x & 31;      // dims 4*l32 .. 4*l32+3
    int node = blockIdx.x * 8 + h;   // grid = 6250, exact
    float di = dinv[node];
    float a0 = 0.f, a1 = 0.f, a2 = 0.f, a3 = 0.f;
    int lo = offs[node], hi = offs[node + 1];
    int e = lo;
    for (; e + 8 <= hi; e += 8) {
        unsigned p0 = epack[e + 0], p1 = epack[e + 1], p2 = epack[e + 2], p3 = epack[e + 3];
        unsigned p4 = epack[e + 4], p5 = epack[e + 5], p6 = epack[e + 6], p7 = epack[e + 7];
        unsigned u0 = T32[(size_t)(p0 & 0xffff) * 32 + l32];
        unsigned u1 = T32[(size_t)(p1 & 0xffff) * 32 + l32];
        unsigned u2 = T32[(size_t)(p2 & 0xffff) * 32 + l32];
        unsigned u3 = T32[(size_t)(p3 & 0xffff) * 32 + l32];
        unsigned u4 = T32[(size_t)(p4 & 0xffff) * 32 + l32];
        unsigned u5 = T32[(size_t)(p5 & 0xffff) * 32 + l32];
        unsigned u6 = T32[(size_t)(p6 & 0xffff) * 32 + l32];
        unsigned u7 = T32[(size_t)(p7 & 0xffff) * 32 + l32];
        float c0 = __half2float(__ushort_as_half((unsigned short)(p0 >> 16)));
        float c1 = __half2float(__ushort_as_half((unsigned short)(p1 >> 16)));
        float c2 = __half2float(__ushort_as_half((unsigned short)(p2 >> 16)));
        float c3 = __half2float(__ushort_as_half((unsigned short)(p3 >> 16)));
        float c4 = __half2float(__ushort_as_half((unsigned short)(p4 >> 16)));
        float c5 = __half2float(__ushort_as_half((unsigned short)(p5 >> 16)));
        float c6 = __half2float(__ushort_as_half((unsigned short)(p6 >> 16)));
        float c7 = __half2float(__ushort_as_half((unsigned short)(p7 >> 16)));
        f32x2 lo0 = __builtin_amdgcn_cvt_pk_f32_fp8(u0, false), hi0 = __builtin_amdgcn_cvt_pk_f32_fp8(u0, true);
        f32x2 lo1 = __builtin_amdgcn_cvt_pk_f32_fp8(u1, false), hi1 = __builtin_amdgcn_cvt_pk_f32_fp8(u1, true);
        f32x2 lo2 = __builtin_amdgcn_cvt_pk_f32_fp8(u2, false), hi2 = __builtin_amdgcn_cvt_pk_f32_fp8(u2, true);
        f32x2 lo3 = __builtin_amdgcn_cvt_pk_f32_fp8(u3, false), hi3 = __builtin_amdgcn_cvt_pk_f32_fp8(u3, true);
        f32x2 lo4 = __builtin_amdgcn_cvt_pk_f32_fp8(u4, false), hi4 = __builtin_amdgcn_cvt_pk_f32_fp8(u4, true);
        f32x2 lo5 = __builtin_amdgcn_cvt_pk_f32_fp8(u5, false), hi5 = __builtin_amdgcn_cvt_pk_f32_fp8(u5, true);
        f32x2 lo6 = __builtin_amdgcn_cvt_pk_f32_fp8(u6, false), hi6 = __builtin_amdgcn_cvt_pk_f32_fp8(u6, true);
        f32x2 lo7 = __builtin_amdgcn_cvt_pk_f32_fp8(u7, false), hi7 = __builtin_amdgcn_cvt_pk_f32_fp8(u7, true);
        a0 += lo0.x * c0; a1 += lo0.y * c0; a2 += hi0.x * c0; a3 += hi0.y * c0;
        a0 += lo1.x * c1; a1 += lo1.y * c1; a2 += hi1.x * c1; a3 += hi1.y * c1;
        a0 += lo2.x * c2; a1 += lo2.y * c2; a2 += hi2.x * c2; a3 += hi2.y * c2;
        a0 += lo3.x * c3; a1 += lo3.y * c3; a2 += hi3.x * c3; a3 += hi3.y * c3;
        a0 += lo4.x * c4; a1 += lo4.y * c4; a2 += hi4.x * c4; a3 += hi4.y * c4;
        a0 += lo5.x * c5; a1 += lo5.y * c5; a2 += hi5.x * c5; a3 += hi5.y * c5;
        a0 += lo6.x * c6; a1 += lo6.y * c6; a2 += hi6.x * c6; a3 += hi6.y * c6;
        a0 += lo7.x * c7; a1 += lo7.y * c7; a2 += hi7.x * c7; a3 += hi7.y * c7;
    }
    for (; e + 4 <= hi; e += 4) {   // 4-deep remainder: keep 4 row loads in flight
        unsigned p0 = epack[e + 0], p1 = epack[e + 1], p2 = epack[e + 2], p3 = epack[e + 3];
        unsigned u0 = T32[(size_t)(p0 & 0xffff) * 32 + l32];
        unsigned u1 = T32[(size_t)(p1 & 0xffff) * 32 + l32];
        unsigned u2 = T32[(size_t)(p2 & 0xffff) * 32 + l32];
        unsigned u3 = T32[(size_t)(p3 & 0xffff) * 32 + l32];
        float c0 = __half2float(__ushort_as_half((unsigned short)(p0 >> 16)));
        float c1 = __half2float(__ushort_as_half((unsigned short)(p1 >> 16)));
        float c2 = __half2float(__ushort_as_half((unsigned short)(p2 >> 16)));
        float c3 = __half2float(__ushort_as_half((unsigned short)(p3 >> 16)));
        f32x2 lo0 = __builtin_amdgcn_cvt_pk_f32_fp8(u0, false), hi0 = __builtin_amdgcn_cvt_pk_f32_fp8(u0, true);
        f32x2 lo1 = __builtin_amdgcn_cvt_pk_f32_fp8(u1, false), hi1 = __builtin_amdgcn_cvt_pk_f32_fp8(u1, true);
        f32x2 lo2 = __builtin_amdgcn_cvt_pk_f32_fp8(u2, false), hi2 = __builtin_amdgcn_cvt_pk_f32_fp8(u2, true);
        f32x2 lo3 = __builtin_amdgcn_cvt_pk_f32_fp8(u3, false), hi3 = __builtin_amdgcn_cvt_pk_f32_fp8(u3, true);
        a0 += lo0.x * c0; a1 += lo0.y * c0; a2 += hi0.x * c0; a3 += hi0.y * c0;
        a0 += lo1.x * c1; a1 += lo1.y * c1; a2 += hi1.x * c1; a3 += hi1.y * c1;
        a0 += lo2.x * c2; a1 += lo2.y * c2; a2 += hi2.x * c2; a3 += hi2.y * c2;
        a0 += lo3.x * c3; a1 += lo3.y * c3; a2 += hi3.x * c3; a3 += hi3.y * c3;
    }
    for (; e < hi; ++e) {
        unsigned p = epack[e];
        float c = __half2float(__ushort_as_half((unsigned short)(p >> 16)));
        unsigned u = T32[(size_t)(p & 0xffff) * 32 + l32];
        f32x2 tl = __builtin_amdgcn_cvt_pk_f32_fp8(u, false), th = __builtin_amdgcn_cvt_pk_f32_fp8(u, true);
        a0 += tl.x * c; a1 += tl.y * c; a2 += th.x * c; a3 += th.y * c;
    }
    unsigned su = T32[(size_t)node * 32 + l32];
    f32x2 sl = __builtin_amdgcn_cvt_pk_f32_fp8(su, false), sh = __builtin_amdgcn_cvt_pk_f32_fp8(su, true);
    float4 b4 = *(const float4*)(bias + l32 * 4);
    float dd = di * di;
    float r0 = di * a0 + sl.x * dd + b4.x;
    float r1 = di * a1 + sl.y * dd + b4.y;
    float r2 = di * a2 + sh.x * dd + b4.z;
    float r3 = di * a3 + sh.y * dd + b4.w;
    H2[(size_t)node * 64 + l32 * 2]     = __floats2half2_rn(r0, r1);
    H2[(size_t)node * 64 + l32 * 2 + 1] = __floats2half2_rn(r2, r3);
}

// ---------------- segment-sum pooling, all 3 layers in one dispatch ----------------
// grid = 64 graphs x 16 chunks, 256 threads = 4 rows x 64 lane-pairs. Bounds search once.
__global__ __launch_bounds__(256) void pool_kernel(const __half2* __restrict__ H0,
                                                   const __half2* __restrict__ H1,
                                                   const __half2* __restrict__ H2buf,
                                                   const int* __restrict__ batch,
                                                   float* __restrict__ pooled) {
    __shared__ int bounds[2];
    __shared__ float2 red[256];
    int g = blockIdx.x >> 4;        // / POOL_CHUNKS
    int chunk = blockIdx.x & (POOL_CHUNKS - 1);
    int tid = threadIdx.x;
    int d2 = tid & 63, sub = tid >> 6;  // 4 row-accumulators
    if (tid < 2) {
        int target = g + tid;  // lower_bound(batch, target)
        int lo = 0, hi = N_NODES;
        while (lo < hi) {
            int mid = (lo + hi) >> 1;
            if (batch[mid] < target) lo = mid + 1; else hi = mid;
        }
        bounds[tid] = lo;
    }
    __syncthreads();
    int lo = bounds[0], hi = bounds[1];
    int n = hi - lo;
    int per = (n + POOL_CHUNKS - 1) / POOL_CHUNKS;
    int s = lo + chunk * per;
    int e = s + per; if (e > hi) e = hi;
    const __half2* Hs[3] = {H0, H1, H2buf};
    for (int l = 0; l < 3; ++l) {
        const __half2* H = Hs[l];
        float ax = 0.0f, ay = 0.0f;
        for (int r = s + sub; r < e; r += 4) {
            float2 v = __half22float2(H[(size_t)r * 64 + d2]);
            ax += v.x; ay += v.y;
        }
        red[tid] = make_float2(ax, ay);
        __syncthreads();
        if (sub == 0 && s < e) {
            float2 v0 = red[d2], v1 = red[64 + d2], v2 = red[128 + d2], v3 = red[192 + d2];
            atomicAdd(&pooled[g * H3 + l * 128 + d2 * 2],     v0.x + v1.x + v2.x + v3.x);
            atomicAdd(&pooled[g * H3 + l * 128 + d2 * 2 + 1], v0.y + v1.y + v2.y + v3.y);
        }
        __syncthreads();
    }
}

// ---------------- MLP head + log_softmax, one block per graph; cnt via binary search ----------------
__global__ __launch_bounds__(384) void mlp_kernel(const float* __restrict__ pooled,
                                                  const int* __restrict__ batch,
                                                  const float* __restrict__ l1W, const float* __restrict__ l1b,
                                                  const float* __restrict__ l2W, const float* __restrict__ l2b,
                                                  float* __restrict__ out) {
    __shared__ float p[H3];
    __shared__ float hid[H3];
    __shared__ float o10[OUTD];
    __shared__ int bnd[2];
    int g = blockIdx.x, tid = threadIdx.x;
    if (tid < 2) {
        int target = g + tid;  // lower_bound(batch, target)
        int lo = 0, hi = N_NODES;
        while (lo < hi) {
            int mid = (lo + hi) >> 1;
            if (batch[mid] < target) lo = mid + 1; else hi = mid;
        }
        bnd[tid] = lo;
    }
    __syncthreads();
    float inv = 1.0f / fmaxf((float)(bnd[1] - bnd[0]), 1.0f);
    p[tid] = pooled[g * H3 + tid] * inv;
    __syncthreads();
    float acc = l1b[tid];
    for (int k = 0; k < H3; ++k) acc += p[k] * l1W[k * H3 + tid];
    hid[tid] = fmaxf(acc, 0.0f);
    __syncthreads();
    if (tid < OUTD) {
        float o = l2b[tid];
        for (int k = 0; k < H3; ++k) o += hid[k] * l2W[k * OUTD + tid];
        o10[tid] = o;
        out[g * OUTD + tid] = o;
    }
    __syncthreads();
    if (tid == 0) {
        float m = o10[0];
        for (int j = 1; j < OUTD; ++j) m = fmaxf(m, o10[j]);
        float s = 0.0f;
        for (int j = 0; j < OUTD; ++j) s += expf(o10[j] - m);
        float lse = m + logf(s);
        for (int j = 0; j < OUTD; ++j) out[N_GRAPHS * OUTD + g * OUTD + j] = o10[j] - lse;
    }
}

extern "C" void kernel_launch(void* const* d_in, const int* in_sizes, int n_in,
                              void* d_out, int out_size, void* d_ws, size_t ws_size,
                              hipStream_t stream) {
    const float* x      = (const float*)d_in[0];
    const float* W1     = (const float*)d_in[1];
    const float* b1     = (const float*)d_in[2];
    const float* W2     = (const float*)d_in[3];
    const float* b2     = (const float*)d_in[4];
    const float* W3     = (const float*)d_in[5];
    const float* b3     = (const float*)d_in[6];
    const float* lin1_W = (const float*)d_in[7];
    const float* lin1_b = (const float*)d_in[8];
    const float* lin2_W = (const float*)d_in[9];
    const float* lin2_b = (const float*)d_in[10];
    const int* edge_index = (const int*)d_in[11];
    const int* batch      = (const int*)d_in[12];

    char* ws = (char*)d_ws;
    auto alloc = [&](size_t bytes) -> void* {
        void* p = (void*)ws;
        ws += (bytes + 255) & ~(size_t)255;
        return p;
    };
    int*   deg    = (int*)  alloc((size_t)N_NODES * 4);
    int*   part   = (int*)  alloc((size_t)SCAN_BLOCKS * 4);
    int*   pbase  = (int*)  alloc((size_t)SCAN_BLOCKS * 4);
    int*   offs   = (int*)  alloc((size_t)(N_NODES + 1) * 4);
    int*   rank   = (int*)  alloc((size_t)N_EDGES * 4);
    float* dinv   = (float*)alloc((size_t)N_NODES * 4);
    unsigned int* epack = (unsigned int*)alloc((size_t)N_EDGES * 4);
    unsigned char* T = (unsigned char*)alloc((size_t)N_NODES * 128);
    __half* Hbuf[3];
    for (int l = 0; l < 3; ++l) Hbuf[l] = (__half*)alloc((size_t)N_NODES * 128 * 2);
    _Float16* Wt  = (_Float16*)alloc((size_t)3 * 128 * 128 * 2);
    float* pooled = (float*)alloc((size_t)N_GRAPHS * H3 * 4);

    hipMemsetAsync(deg, 0, (size_t)N_NODES * 4, stream);
    k_deg<<<(N_EDGES + 255) / 256, 256, 0, stream>>>(edge_index, deg, rank);
    k_part<<<SCAN_BLOCKS, 256, 0, stream>>>(deg, part);
    k_scanpart<<<1, 256, 0, stream>>>(part, pbase);
    k_offsets<<<SCAN_BLOCKS, 256, 0, stream>>>(deg, pbase, offs, dinv);
    k_fill<<<(N_EDGES + 255) / 256, 256, 0, stream>>>(edge_index, offs, rank, dinv, epack);
    k_prep<<<288, 256, 0, stream>>>(W1, W2, W3, Wt, pooled);

    const float* bs[3] = {b1, b2, b3};
    for (int l = 0; l < 3; ++l) {
        if (l == 0)
            gemm_mfma<false><<<(N_NODES + 63) / 64, 256, 0, stream>>>(x, Wt, T, N_NODES);
        else
            gemm_mfma<true><<<(N_NODES + 63) / 64, 256, 0, stream>>>(Hbuf[l - 1], Wt + (size_t)l * 16384, T, N_NODES);
        gather_agg<<<N_NODES / 8, 256, 0, stream>>>((const unsigned int*)T, epack, offs, dinv, bs[l], (__half2*)Hbuf[l]);
    }
    pool_kernel<<<N_GRAPHS * POOL_CHUNKS, 256, 0, stream>>>((const __half2*)Hbuf[0], (const __half2*)Hbuf[1],
                                                            (const __half2*)Hbuf[2], batch, pooled);
    mlp_kernel<<<N_GRAPHS, 384, 0, stream>>>(pooled, batch, lin1_W, lin1_b, lin2_W, lin2_b, (float*)d_out);
}